// Round 6
// baseline (321.880 us; speedup 1.0000x reference)
//
#include <hip/hip_runtime.h>

#define EPS 1e-6f

constexpr int D    = 128;   // head_dim
constexpr int SEQ  = 4096;  // seq_len
constexpr int NBH  = 64;    // bsz*num_heads
constexpr int KB   = 32;    // k rows per LDS tile (pass 1)
constexpr int KSTR = 40;    // padded k-stride (elems) for transposed tiles (80 B = 5x16B)
constexpr int QT   = 64;    // q rows per block (pass 2)

typedef __attribute__((ext_vector_type(8)))  __bf16 bf16x8;
typedef __attribute__((ext_vector_type(4)))  __bf16 bf16x4;
typedef __attribute__((ext_vector_type(4)))  float  f32x4;
typedef __attribute__((ext_vector_type(16))) float  f32x16;

__device__ __forceinline__ float phi1(float x) {
    // elu(x)+1 : x>0 -> x+1 ; x<=0 -> exp(x). Branchless.
    return fmaxf(x, 0.0f) + __expf(fminf(x, 0.0f));
}

// ---------------- Pass 1 (MFMA): KVTp[split][bh][e][d] = sum_k V[k][e]*phiK[k][d] (f32 partials)
// Double-buffered LDS, ONE barrier per tile. 8 waves: 0-3 stage K(+phi,+Z), 4-7 stage V;
// all waves compute 32e x 64d strips via mfma_f32_32x32x16_bf16.
__global__ __launch_bounds__(512, 8) void kv_partial_mfma(const float* __restrict__ K,
                                                          const float* __restrict__ V,
                                                          float* __restrict__ KVTp,
                                                          float* __restrict__ Zp,
                                                          int chunk) {
    __shared__ __bf16 sKT[2][D * KSTR];   // [buf][d][k], phi applied  (20 KB)
    __shared__ __bf16 sVT[2][D * KSTR];   // [buf][e][k]               (20 KB)
    // total 40960 B -> exactly 4 blocks/CU

    const int bh = blockIdx.x, split = blockIdx.y;
    const int tid  = threadIdx.x;
    const int lane = tid & 63;
    const int wave = tid >> 6;
    const int k0   = split * chunk;
    const size_t base = (size_t)bh * SEQ * D;

    // staging role
    const int  ts  = tid & 255;
    const int  kq  = ts & 7;          // k-quad: stages k-local rows kq*4 .. kq*4+3
    const int  cs  = (ts >> 3) * 4;   // column base (d for K-waves, e for V-waves)
    const bool isK = (tid < 256);
    const float* __restrict__ src = isK ? K : V;

    f32x16 acc0, acc1;
#pragma unroll
    for (int i = 0; i < 16; ++i) { acc0[i] = 0.f; acc1[i] = 0.f; }
    float4 zacc = make_float4(0.f, 0.f, 0.f, 0.f);

    const int tiles = chunk / KB;

    // preload tile 0 (4 consecutive k rows, 4 columns)
    float4 p0, p1, p2, p3;
    {
        const size_t g = base + (size_t)(k0 + kq * 4) * D + cs;
        p0 = *(const float4*)(src + g);
        p1 = *(const float4*)(src + g + D);
        p2 = *(const float4*)(src + g + 2 * D);
        p3 = *(const float4*)(src + g + 3 * D);
    }

    const int erow = (wave >> 1) * 32 + (lane & 31);   // A-fragment row (e)
    const int drow = (wave & 1) * 64 + (lane & 31);    // B-fragment col (d), strip 0
    const int kh   = (lane >> 5) * 8;                  // k-half within a 16-k step

    for (int tt = 0; tt < tiles; ++tt) {
        const int buf = tt & 1;
        __bf16* kt = &sKT[buf][0];
        __bf16* vt = &sVT[buf][0];

        // write staged registers into this tile's buffer
        if (isK) {
#define STAGE_K(i, CMP) { \
            float a0 = phi1(p0.CMP), a1 = phi1(p1.CMP), a2 = phi1(p2.CMP), a3 = phi1(p3.CMP); \
            zacc.CMP += a0 + a1 + a2 + a3; \
            bf16x4 wv; wv[0] = (__bf16)a0; wv[1] = (__bf16)a1; wv[2] = (__bf16)a2; wv[3] = (__bf16)a3; \
            *(bf16x4*)(&kt[(cs + i) * KSTR + kq * 4]) = wv; }
            STAGE_K(0, x) STAGE_K(1, y) STAGE_K(2, z) STAGE_K(3, w)
#undef STAGE_K
        } else {
#define STAGE_V(i, CMP) { \
            bf16x4 wv; wv[0] = (__bf16)p0.CMP; wv[1] = (__bf16)p1.CMP; \
            wv[2] = (__bf16)p2.CMP; wv[3] = (__bf16)p3.CMP; \
            *(bf16x4*)(&vt[(cs + i) * KSTR + kq * 4]) = wv; }
            STAGE_V(0, x) STAGE_V(1, y) STAGE_V(2, z) STAGE_V(3, w)
#undef STAGE_V
        }
        __syncthreads();   // the ONLY barrier per tile: writes visible; also drains
                           // (via lgkmcnt) last iter's fragment reads before next overwrite

        // issue next tile's global loads — consumed at next iteration's LDS write
        if (tt + 1 < tiles) {
            const size_t g = base + (size_t)(k0 + (tt + 1) * KB + kq * 4) * D + cs;
            p0 = *(const float4*)(src + g);
            p1 = *(const float4*)(src + g + D);
            p2 = *(const float4*)(src + g + 2 * D);
            p3 = *(const float4*)(src + g + 3 * D);
        }

        // 2 k-steps of 16
#pragma unroll
        for (int ks = 0; ks < KB; ks += 16) {
            const bf16x8 af  = *(const bf16x8*)(&vt[erow * KSTR + ks + kh]);
            const bf16x8 bf0 = *(const bf16x8*)(&kt[drow * KSTR + ks + kh]);
            const bf16x8 bf1 = *(const bf16x8*)(&kt[(drow + 32) * KSTR + ks + kh]);
            acc0 = __builtin_amdgcn_mfma_f32_32x32x16_bf16(af, bf0, acc0, 0, 0, 0);
            acc1 = __builtin_amdgcn_mfma_f32_32x32x16_bf16(af, bf1, acc1, 0, 0, 0);
        }
    }

    // store C partials (f32). C/D: col = lane&31, row = (reg&3) + 8*(reg>>2) + 4*(lane>>5)
    float* kvb = KVTp + ((size_t)split * NBH + bh) * D * D;
    const int ebase = (wave >> 1) * 32 + 4 * (lane >> 5);
    const int dcol  = (wave & 1) * 64 + (lane & 31);
#pragma unroll
    for (int r = 0; r < 16; ++r) {
        const int e = ebase + (r & 3) + 8 * (r >> 2);
        kvb[(size_t)e * D + dcol]      = acc0[r];
        kvb[(size_t)e * D + dcol + 32] = acc1[r];
    }

    // Z partial: the 8 threads sharing a column group are consecutive lanes -> shuffle reduce
    if (isK) {
#pragma unroll
        for (int m = 1; m < 8; m <<= 1) {
            zacc.x += __shfl_xor(zacc.x, m);
            zacc.y += __shfl_xor(zacc.y, m);
            zacc.z += __shfl_xor(zacc.z, m);
            zacc.w += __shfl_xor(zacc.w, m);
        }
        if (kq == 0) {
            *(float4*)(Zp + ((size_t)split * NBH + bh) * D + cs) = zacc;
        }
    }
}

// ---------------- Reduce partials -> bf16: KVT[bh][e][d], Zb[bh][d]
__global__ __launch_bounds__(256) void reduce_bf16_kernel(const float* __restrict__ KVTp,
                                                          const float* __restrict__ Zp,
                                                          __bf16* __restrict__ KVT,
                                                          __bf16* __restrict__ Zb,
                                                          int P) {
    constexpr int KVF8 = NBH * D * D / 8;  // 131072
    constexpr int ZF8  = NBH * D / 8;      // 1024
    const int idx = blockIdx.x * 256 + threadIdx.x;
    if (idx < KVF8) {
        const size_t b0 = (size_t)idx * 8;
        float4 s0 = *(const float4*)(KVTp + b0);
        float4 s1 = *(const float4*)(KVTp + b0 + 4);
        for (int s = 1; s < P; ++s) {
            const float* p = KVTp + (size_t)s * NBH * D * D + b0;
            const float4 a = *(const float4*)(p);
            const float4 b = *(const float4*)(p + 4);
            s0.x += a.x; s0.y += a.y; s0.z += a.z; s0.w += a.w;
            s1.x += b.x; s1.y += b.y; s1.z += b.z; s1.w += b.w;
        }
        bf16x8 o;
        o[0] = (__bf16)s0.x; o[1] = (__bf16)s0.y; o[2] = (__bf16)s0.z; o[3] = (__bf16)s0.w;
        o[4] = (__bf16)s1.x; o[5] = (__bf16)s1.y; o[6] = (__bf16)s1.z; o[7] = (__bf16)s1.w;
        *(bf16x8*)(KVT + b0) = o;
    } else if (idx < KVF8 + ZF8) {
        const size_t b0 = (size_t)(idx - KVF8) * 8;
        float4 s0 = *(const float4*)(Zp + b0);
        float4 s1 = *(const float4*)(Zp + b0 + 4);
        for (int s = 1; s < P; ++s) {
            const float* p = Zp + (size_t)s * NBH * D + b0;
            const float4 a = *(const float4*)(p);
            const float4 b = *(const float4*)(p + 4);
            s0.x += a.x; s0.y += a.y; s0.z += a.z; s0.w += a.w;
            s1.x += b.x; s1.y += b.y; s1.z += b.z; s1.w += b.w;
        }
        bf16x8 o;
        o[0] = (__bf16)s0.x; o[1] = (__bf16)s0.y; o[2] = (__bf16)s0.z; o[3] = (__bf16)s0.w;
        o[4] = (__bf16)s1.x; o[5] = (__bf16)s1.y; o[6] = (__bf16)s1.z; o[7] = (__bf16)s1.w;
        *(bf16x8*)(Zb + b0) = o;
    }
}

// ---------------- Pass 2 (MFMA): out[q][e] = (phiQ[q][:] @ KV) / (phiQ[q][:] . Z + EPS)
__global__ __launch_bounds__(256, 3) void attn_out_mfma(const float* __restrict__ Q,
                                                        const __bf16* __restrict__ KVT,
                                                        const __bf16* __restrict__ Zb,
                                                        float* __restrict__ out) {
    __shared__ __bf16 sKVT[D][D];   // 32 KB, row-XOR-swizzled
    __shared__ __bf16 sQ[QT][D];    // 16 KB, row-XOR-swizzled
    __shared__ __bf16 sZ[D];        // 256 B, linear

    const int bh  = blockIdx.x;
    const int q0  = blockIdx.y * QT;
    const int tid = threadIdx.x;
    const int lane = tid & 63;
    const int wave = tid >> 6;
    const size_t base = (size_t)bh * SEQ * D;

    // stage KVT (bf16 global, swizzle: 8-elem seg ^ (row&7))
    {
        const __bf16* kvg = KVT + (size_t)bh * D * D;
#pragma unroll
        for (int j = 0; j < 8; ++j) {
            const int f   = tid + 256 * j;
            const int e   = f >> 4;
            const int seg = f & 15;
            const bf16x8 v = *(const bf16x8*)(kvg + (size_t)f * 8);
            *(bf16x8*)(&sKVT[e][(seg ^ (e & 7)) * 8]) = v;
        }
    }
    if (tid < 16) {
        *(bf16x8*)(&sZ[tid * 8]) = *(const bf16x8*)(Zb + bh * D + tid * 8);
    }
    // stage phi(Q) as bf16, swizzled
    {
#pragma unroll
        for (int j = 0; j < 8; ++j) {
            const int f  = tid + 256 * j;
            const int r  = f >> 5;
            const int c4 = (f & 31) * 4;
            const float4 qv = *(const float4*)(Q + base + (size_t)(q0 + r) * D + c4);
            bf16x4 qb;
            qb[0] = (__bf16)phi1(qv.x); qb[1] = (__bf16)phi1(qv.y);
            qb[2] = (__bf16)phi1(qv.z); qb[3] = (__bf16)phi1(qv.w);
            *(bf16x4*)(&sQ[r][c4 ^ ((r & 7) * 8)]) = qb;
        }
    }
    __syncthreads();

    f32x4 acc[8];
#pragma unroll
    for (int et = 0; et < 8; ++et) acc[et] = (f32x4){0.f, 0.f, 0.f, 0.f};
    f32x4 accz = (f32x4){0.f, 0.f, 0.f, 0.f};

    const int qw   = wave * 16;
    const int lrow = lane & 15;
    const int lq   = lane >> 4;

#pragma unroll
    for (int dblk = 0; dblk < 4; ++dblk) {
        const int dbase = dblk * 32 + lq * 8;
        const int arow  = qw + lrow;
        const bf16x8 af = *(const bf16x8*)(&sQ[arow][dbase ^ ((arow & 7) * 8)]);
        const bf16x8 zf = *(const bf16x8*)(&sZ[dbase]);
        accz = __builtin_amdgcn_mfma_f32_16x16x32_bf16(af, zf, accz, 0, 0, 0);
#pragma unroll
        for (int et = 0; et < 8; ++et) {
            const int brow = et * 16 + lrow;
            const bf16x8 bfr = *(const bf16x8*)(&sKVT[brow][dbase ^ ((brow & 7) * 8)]);
            acc[et] = __builtin_amdgcn_mfma_f32_16x16x32_bf16(af, bfr, acc[et], 0, 0, 0);
        }
    }

    // epilogue: C/D layout col=lane&15, row=(lane>>4)*4+reg
    float inv[4];
#pragma unroll
    for (int r = 0; r < 4; ++r) inv[r] = 1.0f / (accz[r] + EPS);
    float* ob = out + base + (size_t)(q0 + qw + lq * 4) * D + lrow;
#pragma unroll
    for (int r = 0; r < 4; ++r) {
#pragma unroll
        for (int et = 0; et < 8; ++et) {
            ob[(size_t)r * D + et * 16] = acc[et][r] * inv[r];
        }
    }
}

extern "C" void kernel_launch(void* const* d_in, const int* in_sizes, int n_in,
                              void* d_out, int out_size, void* d_ws, size_t ws_size,
                              hipStream_t stream) {
    const float* Q = (const float*)d_in[0];
    const float* K = (const float*)d_in[1];
    const float* V = (const float*)d_in[2];
    float* out = (float*)d_out;

    // ws layout: [KVTp: P*NBH*D*D f32][Zp: P*NBH*D f32][KVT: NBH*D*D bf16][Zb: NBH*D bf16]
    const size_t per_split_f = (size_t)NBH * D * D + (size_t)NBH * D;
    const size_t bf16_bytes  = ((size_t)NBH * D * D + (size_t)NBH * D) * sizeof(__bf16);
    int P = 16;
    while (P > 1 && (size_t)P * per_split_f * sizeof(float) + bf16_bytes > ws_size) P >>= 1;
    const int chunk = SEQ / P;   // multiple of KB=32 for all P in {1,2,4,8,16}

    float*  KVTp = (float*)d_ws;
    float*  Zp   = KVTp + (size_t)P * NBH * D * D;
    __bf16* KVT  = (__bf16*)(Zp + (size_t)P * NBH * D);
    __bf16* Zb   = KVT + (size_t)NBH * D * D;

    kv_partial_mfma<<<dim3(NBH, P), 512, 0, stream>>>(K, V, KVTp, Zp, chunk);

    constexpr int RED_ITEMS = NBH * D * D / 8 + NBH * D / 8;
    reduce_bf16_kernel<<<(RED_ITEMS + 255) / 256, 256, 0, stream>>>(KVTp, Zp, KVT, Zb, P);

    attn_out_mfma<<<dim3(NBH, SEQ / QT), 256, 0, stream>>>(Q, KVT, Zb, out);
}

// Round 8
// 150.234 us; speedup vs baseline: 2.1425x; 2.1425x over previous
//
#include <hip/hip_runtime.h>

#define EPS 1e-6f

constexpr int D    = 128;   // head_dim
constexpr int SEQ  = 4096;  // seq_len
constexpr int NBH  = 64;    // bsz*num_heads
constexpr int KB   = 32;    // k rows per LDS tile (pass 1)
constexpr int KSTR = 40;    // padded k-stride (elems) for transposed tiles (80 B = 5x16B)
constexpr int QT   = 64;    // q rows per block (pass 2)

typedef __attribute__((ext_vector_type(8)))  __bf16 bf16x8;
typedef __attribute__((ext_vector_type(4)))  __bf16 bf16x4;
typedef __attribute__((ext_vector_type(4)))  float  f32x4;
typedef __attribute__((ext_vector_type(16))) float  f32x16;

__device__ __forceinline__ float phi1(float x) {
    // elu(x)+1 : x>0 -> x+1 ; x<=0 -> exp(x). Branchless.
    return fmaxf(x, 0.0f) + __expf(fminf(x, 0.0f));
}

// ---------------- Pass 1 (MFMA): KVTp[split][bh][e][d] = sum_k V[k][e]*phiK[k][d] (f32 partials)
// Double-buffered LDS, ONE barrier per tile. 8 waves: 0-3 stage K(+phi,+Z), 4-7 stage V;
// all waves compute 32e x 64d strips via mfma_f32_32x32x16_bf16.
// NOTE: launch_bounds min-waves/EU = 4 (NOT 8): this kernel needs ~64-90 regs/wave
// (32 acc + 16 prefetch + staging); 8 waves/EU caps at 64 and spills (R6: 593 MB scratch).
__global__ __launch_bounds__(512, 4) void kv_partial_mfma(const float* __restrict__ K,
                                                          const float* __restrict__ V,
                                                          float* __restrict__ KVTp,
                                                          float* __restrict__ Zp,
                                                          int chunk) {
    __shared__ __bf16 sKT[2][D * KSTR];   // [buf][d][k], phi applied  (20 KB)
    __shared__ __bf16 sVT[2][D * KSTR];   // [buf][e][k]               (20 KB)
    // total 40960 B -> 4 blocks/CU by LDS

    const int bh = blockIdx.x, split = blockIdx.y;
    const int tid  = threadIdx.x;
    const int lane = tid & 63;
    const int wave = tid >> 6;
    const int k0   = split * chunk;
    const size_t base = (size_t)bh * SEQ * D;

    // staging role
    const int  ts  = tid & 255;
    const int  kq  = ts & 7;          // k-quad: stages k-local rows kq*4 .. kq*4+3
    const int  cs  = (ts >> 3) * 4;   // column base (d for K-waves, e for V-waves)
    const bool isK = (tid < 256);
    const float* __restrict__ src = isK ? K : V;

    f32x16 acc0, acc1;
#pragma unroll
    for (int i = 0; i < 16; ++i) { acc0[i] = 0.f; acc1[i] = 0.f; }
    float4 zacc = make_float4(0.f, 0.f, 0.f, 0.f);

    const int tiles = chunk / KB;

    // preload tile 0 (4 consecutive k rows, 4 columns)
    float4 p0, p1, p2, p3;
    {
        const size_t g = base + (size_t)(k0 + kq * 4) * D + cs;
        p0 = *(const float4*)(src + g);
        p1 = *(const float4*)(src + g + D);
        p2 = *(const float4*)(src + g + 2 * D);
        p3 = *(const float4*)(src + g + 3 * D);
    }

    const int erow = (wave >> 1) * 32 + (lane & 31);   // A-fragment row (e)
    const int drow = (wave & 1) * 64 + (lane & 31);    // B-fragment col (d), strip 0
    const int kh   = (lane >> 5) * 8;                  // k-half within a 16-k step

    for (int tt = 0; tt < tiles; ++tt) {
        const int buf = tt & 1;
        __bf16* kt = &sKT[buf][0];
        __bf16* vt = &sVT[buf][0];

        // write staged registers into this tile's buffer
        if (isK) {
#define STAGE_K(i, CMP) { \
            float a0 = phi1(p0.CMP), a1 = phi1(p1.CMP), a2 = phi1(p2.CMP), a3 = phi1(p3.CMP); \
            zacc.CMP += a0 + a1 + a2 + a3; \
            bf16x4 wv; wv[0] = (__bf16)a0; wv[1] = (__bf16)a1; wv[2] = (__bf16)a2; wv[3] = (__bf16)a3; \
            *(bf16x4*)(&kt[(cs + i) * KSTR + kq * 4]) = wv; }
            STAGE_K(0, x) STAGE_K(1, y) STAGE_K(2, z) STAGE_K(3, w)
#undef STAGE_K
        } else {
#define STAGE_V(i, CMP) { \
            bf16x4 wv; wv[0] = (__bf16)p0.CMP; wv[1] = (__bf16)p1.CMP; \
            wv[2] = (__bf16)p2.CMP; wv[3] = (__bf16)p3.CMP; \
            *(bf16x4*)(&vt[(cs + i) * KSTR + kq * 4]) = wv; }
            STAGE_V(0, x) STAGE_V(1, y) STAGE_V(2, z) STAGE_V(3, w)
#undef STAGE_V
        }
        __syncthreads();   // the ONLY barrier per tile: writes visible; also drains
                           // (via lgkmcnt) last iter's fragment reads before next overwrite

        // issue next tile's global loads — consumed at next iteration's LDS write
        if (tt + 1 < tiles) {
            const size_t g = base + (size_t)(k0 + (tt + 1) * KB + kq * 4) * D + cs;
            p0 = *(const float4*)(src + g);
            p1 = *(const float4*)(src + g + D);
            p2 = *(const float4*)(src + g + 2 * D);
            p3 = *(const float4*)(src + g + 3 * D);
        }

        // 2 k-steps of 16
#pragma unroll
        for (int ks = 0; ks < KB; ks += 16) {
            const bf16x8 af  = *(const bf16x8*)(&vt[erow * KSTR + ks + kh]);
            const bf16x8 bf0 = *(const bf16x8*)(&kt[drow * KSTR + ks + kh]);
            const bf16x8 bf1 = *(const bf16x8*)(&kt[(drow + 32) * KSTR + ks + kh]);
            acc0 = __builtin_amdgcn_mfma_f32_32x32x16_bf16(af, bf0, acc0, 0, 0, 0);
            acc1 = __builtin_amdgcn_mfma_f32_32x32x16_bf16(af, bf1, acc1, 0, 0, 0);
        }
    }

    // store C partials (f32). C/D: col = lane&31, row = (reg&3) + 8*(reg>>2) + 4*(lane>>5)
    float* kvb = KVTp + ((size_t)split * NBH + bh) * D * D;
    const int ebase = (wave >> 1) * 32 + 4 * (lane >> 5);
    const int dcol  = (wave & 1) * 64 + (lane & 31);
#pragma unroll
    for (int r = 0; r < 16; ++r) {
        const int e = ebase + (r & 3) + 8 * (r >> 2);
        kvb[(size_t)e * D + dcol]      = acc0[r];
        kvb[(size_t)e * D + dcol + 32] = acc1[r];
    }

    // Z partial: the 8 threads sharing a column group are consecutive lanes -> shuffle reduce
    if (isK) {
#pragma unroll
        for (int m = 1; m < 8; m <<= 1) {
            zacc.x += __shfl_xor(zacc.x, m);
            zacc.y += __shfl_xor(zacc.y, m);
            zacc.z += __shfl_xor(zacc.z, m);
            zacc.w += __shfl_xor(zacc.w, m);
        }
        if (kq == 0) {
            *(float4*)(Zp + ((size_t)split * NBH + bh) * D + cs) = zacc;
        }
    }
}

// ---------------- Reduce partials -> bf16: KVT[bh][e][d], Zb[bh][d]
__global__ __launch_bounds__(256) void reduce_bf16_kernel(const float* __restrict__ KVTp,
                                                          const float* __restrict__ Zp,
                                                          __bf16* __restrict__ KVT,
                                                          __bf16* __restrict__ Zb,
                                                          int P) {
    constexpr int KVF8 = NBH * D * D / 8;  // 131072
    constexpr int ZF8  = NBH * D / 8;      // 1024
    const int idx = blockIdx.x * 256 + threadIdx.x;
    if (idx < KVF8) {
        const size_t b0 = (size_t)idx * 8;
        float4 s0 = *(const float4*)(KVTp + b0);
        float4 s1 = *(const float4*)(KVTp + b0 + 4);
        for (int s = 1; s < P; ++s) {
            const float* p = KVTp + (size_t)s * NBH * D * D + b0;
            const float4 a = *(const float4*)(p);
            const float4 b = *(const float4*)(p + 4);
            s0.x += a.x; s0.y += a.y; s0.z += a.z; s0.w += a.w;
            s1.x += b.x; s1.y += b.y; s1.z += b.z; s1.w += b.w;
        }
        bf16x8 o;
        o[0] = (__bf16)s0.x; o[1] = (__bf16)s0.y; o[2] = (__bf16)s0.z; o[3] = (__bf16)s0.w;
        o[4] = (__bf16)s1.x; o[5] = (__bf16)s1.y; o[6] = (__bf16)s1.z; o[7] = (__bf16)s1.w;
        *(bf16x8*)(KVT + b0) = o;
    } else if (idx < KVF8 + ZF8) {
        const size_t b0 = (size_t)(idx - KVF8) * 8;
        float4 s0 = *(const float4*)(Zp + b0);
        float4 s1 = *(const float4*)(Zp + b0 + 4);
        for (int s = 1; s < P; ++s) {
            const float* p = Zp + (size_t)s * NBH * D + b0;
            const float4 a = *(const float4*)(p);
            const float4 b = *(const float4*)(p + 4);
            s0.x += a.x; s0.y += a.y; s0.z += a.z; s0.w += a.w;
            s1.x += b.x; s1.y += b.y; s1.z += b.z; s1.w += b.w;
        }
        bf16x8 o;
        o[0] = (__bf16)s0.x; o[1] = (__bf16)s0.y; o[2] = (__bf16)s0.z; o[3] = (__bf16)s0.w;
        o[4] = (__bf16)s1.x; o[5] = (__bf16)s1.y; o[6] = (__bf16)s1.z; o[7] = (__bf16)s1.w;
        *(bf16x8*)(Zb + b0) = o;
    }
}

// ---------------- Pass 2 (MFMA): out[q][e] = (phiQ[q][:] @ KV) / (phiQ[q][:] . Z + EPS)
__global__ __launch_bounds__(256, 3) void attn_out_mfma(const float* __restrict__ Q,
                                                        const __bf16* __restrict__ KVT,
                                                        const __bf16* __restrict__ Zb,
                                                        float* __restrict__ out) {
    __shared__ __bf16 sKVT[D][D];   // 32 KB, row-XOR-swizzled
    __shared__ __bf16 sQ[QT][D];    // 16 KB, row-XOR-swizzled
    __shared__ __bf16 sZ[D];        // 256 B, linear

    const int bh  = blockIdx.x;
    const int q0  = blockIdx.y * QT;
    const int tid = threadIdx.x;
    const int lane = tid & 63;
    const int wave = tid >> 6;
    const size_t base = (size_t)bh * SEQ * D;

    // stage KVT (bf16 global, swizzle: 8-elem seg ^ (row&7))
    {
        const __bf16* kvg = KVT + (size_t)bh * D * D;
#pragma unroll
        for (int j = 0; j < 8; ++j) {
            const int f   = tid + 256 * j;
            const int e   = f >> 4;
            const int seg = f & 15;
            const bf16x8 v = *(const bf16x8*)(kvg + (size_t)f * 8);
            *(bf16x8*)(&sKVT[e][(seg ^ (e & 7)) * 8]) = v;
        }
    }
    if (tid < 16) {
        *(bf16x8*)(&sZ[tid * 8]) = *(const bf16x8*)(Zb + bh * D + tid * 8);
    }
    // stage phi(Q) as bf16, swizzled
    {
#pragma unroll
        for (int j = 0; j < 8; ++j) {
            const int f  = tid + 256 * j;
            const int r  = f >> 5;
            const int c4 = (f & 31) * 4;
            const float4 qv = *(const float4*)(Q + base + (size_t)(q0 + r) * D + c4);
            bf16x4 qb;
            qb[0] = (__bf16)phi1(qv.x); qb[1] = (__bf16)phi1(qv.y);
            qb[2] = (__bf16)phi1(qv.z); qb[3] = (__bf16)phi1(qv.w);
            *(bf16x4*)(&sQ[r][c4 ^ ((r & 7) * 8)]) = qb;
        }
    }
    __syncthreads();

    f32x4 acc[8];
#pragma unroll
    for (int et = 0; et < 8; ++et) acc[et] = (f32x4){0.f, 0.f, 0.f, 0.f};
    f32x4 accz = (f32x4){0.f, 0.f, 0.f, 0.f};

    const int qw   = wave * 16;
    const int lrow = lane & 15;
    const int lq   = lane >> 4;

#pragma unroll
    for (int dblk = 0; dblk < 4; ++dblk) {
        const int dbase = dblk * 32 + lq * 8;
        const int arow  = qw + lrow;
        const bf16x8 af = *(const bf16x8*)(&sQ[arow][dbase ^ ((arow & 7) * 8)]);
        const bf16x8 zf = *(const bf16x8*)(&sZ[dbase]);
        accz = __builtin_amdgcn_mfma_f32_16x16x32_bf16(af, zf, accz, 0, 0, 0);
#pragma unroll
        for (int et = 0; et < 8; ++et) {
            const int brow = et * 16 + lrow;
            const bf16x8 bfr = *(const bf16x8*)(&sKVT[brow][dbase ^ ((brow & 7) * 8)]);
            acc[et] = __builtin_amdgcn_mfma_f32_16x16x32_bf16(af, bfr, acc[et], 0, 0, 0);
        }
    }

    // epilogue: C/D layout col=lane&15, row=(lane>>4)*4+reg
    float inv[4];
#pragma unroll
    for (int r = 0; r < 4; ++r) inv[r] = 1.0f / (accz[r] + EPS);
    float* ob = out + base + (size_t)(q0 + qw + lq * 4) * D + lrow;
#pragma unroll
    for (int r = 0; r < 4; ++r) {
#pragma unroll
        for (int et = 0; et < 8; ++et) {
            ob[(size_t)r * D + et * 16] = acc[et][r] * inv[r];
        }
    }
}

extern "C" void kernel_launch(void* const* d_in, const int* in_sizes, int n_in,
                              void* d_out, int out_size, void* d_ws, size_t ws_size,
                              hipStream_t stream) {
    const float* Q = (const float*)d_in[0];
    const float* K = (const float*)d_in[1];
    const float* V = (const float*)d_in[2];
    float* out = (float*)d_out;

    // ws layout: [KVTp: P*NBH*D*D f32][Zp: P*NBH*D f32][KVT: NBH*D*D bf16][Zb: NBH*D bf16]
    const size_t per_split_f = (size_t)NBH * D * D + (size_t)NBH * D;
    const size_t bf16_bytes  = ((size_t)NBH * D * D + (size_t)NBH * D) * sizeof(__bf16);
    int P = 16;
    while (P > 1 && (size_t)P * per_split_f * sizeof(float) + bf16_bytes > ws_size) P >>= 1;
    const int chunk = SEQ / P;   // multiple of KB=32 for all P in {1,2,4,8,16}

    float*  KVTp = (float*)d_ws;
    float*  Zp   = KVTp + (size_t)P * NBH * D * D;
    __bf16* KVT  = (__bf16*)(Zp + (size_t)P * NBH * D);
    __bf16* Zb   = KVT + (size_t)NBH * D * D;

    kv_partial_mfma<<<dim3(NBH, P), 512, 0, stream>>>(K, V, KVTp, Zp, chunk);

    constexpr int RED_ITEMS = NBH * D * D / 8 + NBH * D / 8;
    reduce_bf16_kernel<<<(RED_ITEMS + 255) / 256, 256, 0, stream>>>(KVTp, Zp, KVT, Zb, P);

    attn_out_mfma<<<dim3(NBH, SEQ / QT), 256, 0, stream>>>(Q, KVT, Zb, out);
}

// Round 9
// 148.877 us; speedup vs baseline: 2.1620x; 1.0091x over previous
//
#include <hip/hip_runtime.h>

#define EPS 1e-6f

constexpr int D    = 128;   // head_dim
constexpr int SEQ  = 4096;  // seq_len
constexpr int NBH  = 64;    // bsz*num_heads
constexpr int KB   = 32;    // k rows per LDS tile (pass 1)
constexpr int KSTR = 40;    // padded k-stride (elems): 80 B rows -> 16B-aligned, 2-way banks
constexpr int QT   = 64;    // q rows per block (pass 2)

typedef __attribute__((ext_vector_type(8)))  __bf16 bf16x8;
typedef __attribute__((ext_vector_type(4)))  __bf16 bf16x4;
typedef __attribute__((ext_vector_type(4)))  float  f32x4;
typedef __attribute__((ext_vector_type(16))) float  f32x16;

__device__ __forceinline__ float phi1(float x) {
    // elu(x)+1 : x>0 -> x+1 ; x<=0 -> exp(x). Branchless.
    return fmaxf(x, 0.0f) + __expf(fminf(x, 0.0f));
}

// ---------------- Pass 1 (MFMA): KVTp[split][bh][e][d] = sum_k V[k][e]*phiK[k][d] (f32 partials)
// Depth-2 register prefetch (sets A/B, named regs - no runtime indexing) + double-buffered LDS.
// Loads for tile t+2 are issued at tile t, so the vmcnt wait at tile t+2's LDS-write spans
// TWO compute phases (~latency coverage). 8 waves: 0-3 stage K(+phi,+Z), 4-7 stage V.
__global__ __launch_bounds__(512, 4) void kv_partial_mfma(const float* __restrict__ K,
                                                          const float* __restrict__ V,
                                                          float* __restrict__ KVTp,
                                                          float* __restrict__ Zp,
                                                          int chunk) {
    __shared__ __bf16 sKT[2][D * KSTR];   // [buf][d][k], phi applied  (20 KB)
    __shared__ __bf16 sVT[2][D * KSTR];   // [buf][e][k]               (20 KB)

    const int bh = blockIdx.x, split = blockIdx.y;
    const int tid  = threadIdx.x;
    const int lane = tid & 63;
    const int wave = tid >> 6;
    const int k0   = split * chunk;
    const size_t base = (size_t)bh * SEQ * D;

    // staging role
    const int  ts  = tid & 255;
    const int  kq  = ts & 7;          // k-quad: stages k-local rows kq*4 .. kq*4+3
    const int  cs  = (ts >> 3) * 4;   // column base (d for K-waves, e for V-waves)
    const bool isK = (tid < 256);
    const float* __restrict__ src = isK ? K : V;

    f32x16 acc0, acc1;
#pragma unroll
    for (int i = 0; i < 16; ++i) { acc0[i] = 0.f; acc1[i] = 0.f; }
    float4 zacc = make_float4(0.f, 0.f, 0.f, 0.f);

    const int tiles = chunk / KB;   // 8 for P=16 (even; the tt+=2 loop relies on even count)

    float4 pa0, pa1, pa2, pa3;   // prefetch set A
    float4 pb0, pb1, pb2, pb3;   // prefetch set B

#define P1_LOAD(S0, S1, S2, S3, TI) { \
        const size_t g = base + (size_t)(k0 + (TI) * KB + kq * 4) * D + cs; \
        S0 = *(const float4*)(src + g); \
        S1 = *(const float4*)(src + g + D); \
        S2 = *(const float4*)(src + g + 2 * D); \
        S3 = *(const float4*)(src + g + 3 * D); }

#define P1_STAGE(BUF, S0, S1, S2, S3) { \
        __bf16* kt = &sKT[BUF][0]; \
        __bf16* vt = &sVT[BUF][0]; \
        if (isK) { \
            float a0, a1, a2, a3; bf16x4 wv; \
            a0 = phi1(S0.x); a1 = phi1(S1.x); a2 = phi1(S2.x); a3 = phi1(S3.x); \
            zacc.x += a0 + a1 + a2 + a3; \
            wv[0] = (__bf16)a0; wv[1] = (__bf16)a1; wv[2] = (__bf16)a2; wv[3] = (__bf16)a3; \
            *(bf16x4*)(&kt[(cs + 0) * KSTR + kq * 4]) = wv; \
            a0 = phi1(S0.y); a1 = phi1(S1.y); a2 = phi1(S2.y); a3 = phi1(S3.y); \
            zacc.y += a0 + a1 + a2 + a3; \
            wv[0] = (__bf16)a0; wv[1] = (__bf16)a1; wv[2] = (__bf16)a2; wv[3] = (__bf16)a3; \
            *(bf16x4*)(&kt[(cs + 1) * KSTR + kq * 4]) = wv; \
            a0 = phi1(S0.z); a1 = phi1(S1.z); a2 = phi1(S2.z); a3 = phi1(S3.z); \
            zacc.z += a0 + a1 + a2 + a3; \
            wv[0] = (__bf16)a0; wv[1] = (__bf16)a1; wv[2] = (__bf16)a2; wv[3] = (__bf16)a3; \
            *(bf16x4*)(&kt[(cs + 2) * KSTR + kq * 4]) = wv; \
            a0 = phi1(S0.w); a1 = phi1(S1.w); a2 = phi1(S2.w); a3 = phi1(S3.w); \
            zacc.w += a0 + a1 + a2 + a3; \
            wv[0] = (__bf16)a0; wv[1] = (__bf16)a1; wv[2] = (__bf16)a2; wv[3] = (__bf16)a3; \
            *(bf16x4*)(&kt[(cs + 3) * KSTR + kq * 4]) = wv; \
        } else { \
            bf16x4 wv; \
            wv[0] = (__bf16)S0.x; wv[1] = (__bf16)S1.x; wv[2] = (__bf16)S2.x; wv[3] = (__bf16)S3.x; \
            *(bf16x4*)(&vt[(cs + 0) * KSTR + kq * 4]) = wv; \
            wv[0] = (__bf16)S0.y; wv[1] = (__bf16)S1.y; wv[2] = (__bf16)S2.y; wv[3] = (__bf16)S3.y; \
            *(bf16x4*)(&vt[(cs + 1) * KSTR + kq * 4]) = wv; \
            wv[0] = (__bf16)S0.z; wv[1] = (__bf16)S1.z; wv[2] = (__bf16)S2.z; wv[3] = (__bf16)S3.z; \
            *(bf16x4*)(&vt[(cs + 2) * KSTR + kq * 4]) = wv; \
            wv[0] = (__bf16)S0.w; wv[1] = (__bf16)S1.w; wv[2] = (__bf16)S2.w; wv[3] = (__bf16)S3.w; \
            *(bf16x4*)(&vt[(cs + 3) * KSTR + kq * 4]) = wv; \
        } }

#define P1_MFMA(BUF) { \
        const __bf16* kt = &sKT[BUF][0]; \
        const __bf16* vt = &sVT[BUF][0]; \
        _Pragma("unroll") \
        for (int ks = 0; ks < KB; ks += 16) { \
            const bf16x8 af  = *(const bf16x8*)(&vt[erow * KSTR + ks + kh]); \
            const bf16x8 bf0 = *(const bf16x8*)(&kt[drow * KSTR + ks + kh]); \
            const bf16x8 bf1 = *(const bf16x8*)(&kt[(drow + 32) * KSTR + ks + kh]); \
            acc0 = __builtin_amdgcn_mfma_f32_32x32x16_bf16(af, bf0, acc0, 0, 0, 0); \
            acc1 = __builtin_amdgcn_mfma_f32_32x32x16_bf16(af, bf1, acc1, 0, 0, 0); \
        } }

    const int erow = (wave >> 1) * 32 + (lane & 31);   // A-fragment row (e)
    const int drow = (wave & 1) * 64 + (lane & 31);    // B-fragment col (d), strip 0
    const int kh   = (lane >> 5) * 8;                  // k-half within a 16-k step

    // prologue: two tiles in flight
    P1_LOAD(pa0, pa1, pa2, pa3, 0)
    P1_LOAD(pb0, pb1, pb2, pb3, 1)

    for (int tt = 0; tt < tiles; tt += 2) {
        // even tile -> buf0, consumes set A
        P1_STAGE(0, pa0, pa1, pa2, pa3)
        __syncthreads();
        if (tt + 2 < tiles) P1_LOAD(pa0, pa1, pa2, pa3, tt + 2)
        P1_MFMA(0)
        // odd tile -> buf1, consumes set B
        P1_STAGE(1, pb0, pb1, pb2, pb3)
        __syncthreads();
        if (tt + 3 < tiles) P1_LOAD(pb0, pb1, pb2, pb3, tt + 3)
        P1_MFMA(1)
    }
#undef P1_LOAD
#undef P1_STAGE
#undef P1_MFMA

    // store C partials (f32). C/D: col = lane&31, row = (reg&3) + 8*(reg>>2) + 4*(lane>>5)
    float* kvb = KVTp + ((size_t)split * NBH + bh) * D * D;
    const int ebase = (wave >> 1) * 32 + 4 * (lane >> 5);
    const int dcol  = (wave & 1) * 64 + (lane & 31);
#pragma unroll
    for (int r = 0; r < 16; ++r) {
        const int e = ebase + (r & 3) + 8 * (r >> 2);
        kvb[(size_t)e * D + dcol]      = acc0[r];
        kvb[(size_t)e * D + dcol + 32] = acc1[r];
    }

    // Z partial: the 8 threads sharing a column group are consecutive lanes -> shuffle reduce
    if (isK) {
#pragma unroll
        for (int m = 1; m < 8; m <<= 1) {
            zacc.x += __shfl_xor(zacc.x, m);
            zacc.y += __shfl_xor(zacc.y, m);
            zacc.z += __shfl_xor(zacc.z, m);
            zacc.w += __shfl_xor(zacc.w, m);
        }
        if (kq == 0) {
            *(float4*)(Zp + ((size_t)split * NBH + bh) * D + cs) = zacc;
        }
    }
}

// ---------------- Reduce partials -> bf16: KVT[bh][e][d], Zb[bh][d]
__global__ __launch_bounds__(256) void reduce_bf16_kernel(const float* __restrict__ KVTp,
                                                          const float* __restrict__ Zp,
                                                          __bf16* __restrict__ KVT,
                                                          __bf16* __restrict__ Zb,
                                                          int P) {
    constexpr int KVF8 = NBH * D * D / 8;  // 131072
    constexpr int ZF8  = NBH * D / 8;      // 1024
    const int idx = blockIdx.x * 256 + threadIdx.x;
    if (idx < KVF8) {
        const size_t b0 = (size_t)idx * 8;
        float4 s0 = *(const float4*)(KVTp + b0);
        float4 s1 = *(const float4*)(KVTp + b0 + 4);
        for (int s = 1; s < P; ++s) {
            const float* p = KVTp + (size_t)s * NBH * D * D + b0;
            const float4 a = *(const float4*)(p);
            const float4 b = *(const float4*)(p + 4);
            s0.x += a.x; s0.y += a.y; s0.z += a.z; s0.w += a.w;
            s1.x += b.x; s1.y += b.y; s1.z += b.z; s1.w += b.w;
        }
        bf16x8 o;
        o[0] = (__bf16)s0.x; o[1] = (__bf16)s0.y; o[2] = (__bf16)s0.z; o[3] = (__bf16)s0.w;
        o[4] = (__bf16)s1.x; o[5] = (__bf16)s1.y; o[6] = (__bf16)s1.z; o[7] = (__bf16)s1.w;
        *(bf16x8*)(KVT + b0) = o;
    } else if (idx < KVF8 + ZF8) {
        const size_t b0 = (size_t)(idx - KVF8) * 8;
        float4 s0 = *(const float4*)(Zp + b0);
        float4 s1 = *(const float4*)(Zp + b0 + 4);
        for (int s = 1; s < P; ++s) {
            const float* p = Zp + (size_t)s * NBH * D + b0;
            const float4 a = *(const float4*)(p);
            const float4 b = *(const float4*)(p + 4);
            s0.x += a.x; s0.y += a.y; s0.z += a.z; s0.w += a.w;
            s1.x += b.x; s1.y += b.y; s1.z += b.z; s1.w += b.w;
        }
        bf16x8 o;
        o[0] = (__bf16)s0.x; o[1] = (__bf16)s0.y; o[2] = (__bf16)s0.z; o[3] = (__bf16)s0.w;
        o[4] = (__bf16)s1.x; o[5] = (__bf16)s1.y; o[6] = (__bf16)s1.z; o[7] = (__bf16)s1.w;
        *(bf16x8*)(Zb + b0) = o;
    }
}

// ---------------- Pass 2 (MFMA): out[q][e] = (phiQ[q][:] @ KV) / (phiQ[q][:] . Z + EPS)
__global__ __launch_bounds__(256, 3) void attn_out_mfma(const float* __restrict__ Q,
                                                        const __bf16* __restrict__ KVT,
                                                        const __bf16* __restrict__ Zb,
                                                        float* __restrict__ out) {
    __shared__ __bf16 sKVT[D][D];   // 32 KB, row-XOR-swizzled
    __shared__ __bf16 sQ[QT][D];    // 16 KB, row-XOR-swizzled
    __shared__ __bf16 sZ[D];        // 256 B, linear

    const int bh  = blockIdx.x;
    const int q0  = blockIdx.y * QT;
    const int tid = threadIdx.x;
    const int lane = tid & 63;
    const int wave = tid >> 6;
    const size_t base = (size_t)bh * SEQ * D;

    // stage KVT (bf16 global, swizzle: 8-elem seg ^ (row&7))
    {
        const __bf16* kvg = KVT + (size_t)bh * D * D;
#pragma unroll
        for (int j = 0; j < 8; ++j) {
            const int f   = tid + 256 * j;
            const int e   = f >> 4;
            const int seg = f & 15;
            const bf16x8 v = *(const bf16x8*)(kvg + (size_t)f * 8);
            *(bf16x8*)(&sKVT[e][(seg ^ (e & 7)) * 8]) = v;
        }
    }
    if (tid < 16) {
        *(bf16x8*)(&sZ[tid * 8]) = *(const bf16x8*)(Zb + bh * D + tid * 8);
    }
    // stage phi(Q) as bf16, swizzled
    {
#pragma unroll
        for (int j = 0; j < 8; ++j) {
            const int f  = tid + 256 * j;
            const int r  = f >> 5;
            const int c4 = (f & 31) * 4;
            const float4 qv = *(const float4*)(Q + base + (size_t)(q0 + r) * D + c4);
            bf16x4 qb;
            qb[0] = (__bf16)phi1(qv.x); qb[1] = (__bf16)phi1(qv.y);
            qb[2] = (__bf16)phi1(qv.z); qb[3] = (__bf16)phi1(qv.w);
            *(bf16x4*)(&sQ[r][c4 ^ ((r & 7) * 8)]) = qb;
        }
    }
    __syncthreads();

    f32x4 acc[8];
#pragma unroll
    for (int et = 0; et < 8; ++et) acc[et] = (f32x4){0.f, 0.f, 0.f, 0.f};
    f32x4 accz = (f32x4){0.f, 0.f, 0.f, 0.f};

    const int qw   = wave * 16;
    const int lrow = lane & 15;
    const int lq   = lane >> 4;

#pragma unroll
    for (int dblk = 0; dblk < 4; ++dblk) {
        const int dbase = dblk * 32 + lq * 8;
        const int arow  = qw + lrow;
        const bf16x8 af = *(const bf16x8*)(&sQ[arow][dbase ^ ((arow & 7) * 8)]);
        const bf16x8 zf = *(const bf16x8*)(&sZ[dbase]);
        accz = __builtin_amdgcn_mfma_f32_16x16x32_bf16(af, zf, accz, 0, 0, 0);
#pragma unroll
        for (int et = 0; et < 8; ++et) {
            const int brow = et * 16 + lrow;
            const bf16x8 bfr = *(const bf16x8*)(&sKVT[brow][dbase ^ ((brow & 7) * 8)]);
            acc[et] = __builtin_amdgcn_mfma_f32_16x16x32_bf16(af, bfr, acc[et], 0, 0, 0);
        }
    }

    // epilogue: C/D layout col=lane&15, row=(lane>>4)*4+reg
    float inv[4];
#pragma unroll
    for (int r = 0; r < 4; ++r) inv[r] = 1.0f / (accz[r] + EPS);
    float* ob = out + base + (size_t)(q0 + qw + lq * 4) * D + lrow;
#pragma unroll
    for (int r = 0; r < 4; ++r) {
#pragma unroll
        for (int et = 0; et < 8; ++et) {
            ob[(size_t)r * D + et * 16] = acc[et][r] * inv[r];
        }
    }
}

extern "C" void kernel_launch(void* const* d_in, const int* in_sizes, int n_in,
                              void* d_out, int out_size, void* d_ws, size_t ws_size,
                              hipStream_t stream) {
    const float* Q = (const float*)d_in[0];
    const float* K = (const float*)d_in[1];
    const float* V = (const float*)d_in[2];
    float* out = (float*)d_out;

    // ws layout: [KVTp: P*NBH*D*D f32][Zp: P*NBH*D f32][KVT: NBH*D*D bf16][Zb: NBH*D bf16]
    const size_t per_split_f = (size_t)NBH * D * D + (size_t)NBH * D;
    const size_t bf16_bytes  = ((size_t)NBH * D * D + (size_t)NBH * D) * sizeof(__bf16);
    int P = 16;
    while (P > 1 && (size_t)P * per_split_f * sizeof(float) + bf16_bytes > ws_size) P >>= 1;
    const int chunk = SEQ / P;   // multiple of 2*KB=64 for all P in {1,2,4,8,16}

    float*  KVTp = (float*)d_ws;
    float*  Zp   = KVTp + (size_t)P * NBH * D * D;
    __bf16* KVT  = (__bf16*)(Zp + (size_t)P * NBH * D);
    __bf16* Zb   = KVT + (size_t)NBH * D * D;

    kv_partial_mfma<<<dim3(NBH, P), 512, 0, stream>>>(K, V, KVTp, Zp, chunk);

    constexpr int RED_ITEMS = NBH * D * D / 8 + NBH * D / 8;
    reduce_bf16_kernel<<<(RED_ITEMS + 255) / 256, 256, 0, stream>>>(KVTp, Zp, KVT, Zb, P);

    attn_out_mfma<<<dim3(NBH, SEQ / QT), 256, 0, stream>>>(Q, KVT, Zb, out);
}